// Round 28
// baseline (72.476 us; speedup 1.0000x reference)
//
#include <hip/hip_runtime.h>

typedef float f32x4 __attribute__((ext_vector_type(4)));
typedef int   int4v __attribute__((ext_vector_type(4)));
typedef int   int8v __attribute__((ext_vector_type(8)));

#define AS1 __attribute__((address_space(1)))
#define AS3 __attribute__((address_space(3)))

#define NROWS 2048
#define NCOLS 100000
#define NPAD  100352              // 98 chunks * 1024
#define NCHUNK 98
#define K2C  28.853900817779268f  // 20 * log2(e)
#define PADC 7.2552607e-7f        // 352 * exp(-20): pad-column bias
#define SCLA 0x7F7F7F7Fu          // E8M0 scale 2^0  (A already x K2C)
#define SCLB 0x7C7C7C7Cu          // E8M0 scale 2^-3 (B pre-scaled x 8)

// ---- merged prep (blocks 0..511) + feature f32->fp8 conv (rest) ----
__global__ void k_pc(const float* __restrict__ X, const int* __restrict__ idx,
                     const int* __restrict__ lab, const float* __restrict__ F,
                     unsigned short* __restrict__ A8, float* __restrict__ picked,
                     unsigned char* __restrict__ Fq) {
  if (blockIdx.x < 512) {
    // normalize inputs, scale by K2C, convert to fp8 e4m3; also picked
    int wid = threadIdx.x >> 6, lane = threadIdx.x & 63;
    int row = blockIdx.x * 4 + wid;
    int t = lab[idx[row]];
    float2 v = ((const float2*)(X + (size_t)row * 128))[lane];
    float2 f = ((const float2*)(F + (size_t)t * 128))[lane];
    float ss = v.x * v.x + v.y * v.y;
    float dp = v.x * f.x + v.y * f.y;
#pragma unroll
    for (int m = 1; m < 64; m <<= 1) {
      ss += __shfl_xor(ss, m, 64);
      dp += __shfl_xor(dp, m, 64);
    }
    float invn = 1.0f / fmaxf(sqrtf(ss), 1e-12f);
    float s = invn * K2C;             // fold 20*log2(e) into A
    int w = __builtin_amdgcn_cvt_pk_fp8_f32(v.x * s, v.y * s, 0, false);
    A8[row * 64 + lane] = (unsigned short)(w & 0xFFFF);
    if (lane == 0) picked[row] = 20.0f * dp * invn;
  } else {
    // features f32 -> fp8 e4m3 (x8), zero-pad [100000,100352)
    const int NG16 = NPAD * 8;   // 802,816 groups of 16 output bytes
    const int NV16 = NCOLS * 8;  // 800,000 valid groups
    int stride = 1568 * 256;
    for (int g = (blockIdx.x - 512) * 256 + threadIdx.x; g < NG16; g += stride) {
      float4 a = make_float4(0.f, 0.f, 0.f, 0.f), b = a, c = a, d = a;
      if (g < NV16) {
        const float4* p = (const float4*)F + 4 * (size_t)g;
        a = p[0]; b = p[1]; c = p[2]; d = p[3];
      }
      int w0 = __builtin_amdgcn_cvt_pk_fp8_f32(a.x * 8.f, a.y * 8.f, 0, false);
      w0 = __builtin_amdgcn_cvt_pk_fp8_f32(a.z * 8.f, a.w * 8.f, w0, true);
      int w1 = __builtin_amdgcn_cvt_pk_fp8_f32(b.x * 8.f, b.y * 8.f, 0, false);
      w1 = __builtin_amdgcn_cvt_pk_fp8_f32(b.z * 8.f, b.w * 8.f, w1, true);
      int w2 = __builtin_amdgcn_cvt_pk_fp8_f32(c.x * 8.f, c.y * 8.f, 0, false);
      w2 = __builtin_amdgcn_cvt_pk_fp8_f32(c.z * 8.f, c.w * 8.f, w2, true);
      int w3 = __builtin_amdgcn_cvt_pk_fp8_f32(d.x * 8.f, d.y * 8.f, 0, false);
      w3 = __builtin_amdgcn_cvt_pk_fp8_f32(d.z * 8.f, d.w * 8.f, w3, true);
      ((int4v*)Fq)[g] = (int4v){w0, w1, w2, w3};
    }
  }
}

// ---- fused GEMM + sum of exp(logit - 20), MX-fp8 K=128, PAIRED HALVES ----
// grid = 832 = 8 xcd * 104 slots; all 8 m-tiles of a chunk share one XCD.
// Ring of 4 x 8KB slots (32 KB); halves processed in PAIRS: super-phase j
// interleaves phase j of half 2i and 2i+1 -> TWO independent dep chains
// (8 indep MFMAs + 32 exp2) fill each other's MFMA-latency shadow within
// the wave. One vmcnt(0)+barrier per pair (prefetch lead = full pair).
// r25 config: best measured total. Practical plateau: the per-phase chain
// {ds_read -> MFMA -> exp2 tail} cannot be broken without a second acc set
// (+32-64 VGPR, crosses the 128-VGPR occupancy boundary; verified r11/r20).
__global__ __launch_bounds__(256, 2) void k_gemm(
    const unsigned short* __restrict__ A8,
    const unsigned char* __restrict__ Fq,
    float* __restrict__ part) {
  __shared__ unsigned char ring[4][64 * 128];     // 32 KB ring (fp8)
  __shared__ float xpose[4][64];                  // part-store transpose
  const int tid = threadIdx.x;
  const int wid = tid >> 6, lane = tid & 63;
  const int lrow = lane & 15, lk = lane >> 4;

  const int slot = blockIdx.x >> 3;     // [0,104)
  const int xcd  = blockIdx.x & 7;
  const int mtile = slot & 7;
  const int chunk = (slot >> 3) * 8 + xcd;
  if (chunk >= NCHUNK) return;
  const int row0 = mtile * 256 + wid * 64;

  // A fragments: 32 fp8 (full K strip) per lane per mf-tile = 32 VGPR total
  const unsigned char* A8b = (const unsigned char*)A8;
  int8v af[4];
#pragma unroll
  for (int mf = 0; mf < 4; ++mf) {
    const unsigned char* ap = A8b + (size_t)(row0 + mf * 16 + lrow) * 128 + lk * 32;
    ((int4v*)&af[mf])[0] = *(const int4v*)ap;
    ((int4v*)&af[mf])[1] = *(const int4v*)(ap + 16);
  }

  // vector accumulators -> v_pk_add_f32
  f32x4 racc[4];
#pragma unroll
  for (int mf = 0; mf < 4; ++mf) racc[mf] = (f32x4){0.f, 0.f, 0.f, 0.f};

  // loop-invariant C operand: folds the -20 shift
  f32x4 cinit = (f32x4){-K2C, -K2C, -K2C, -K2C};

  // hoisted ds_read lane offsets: off[j][0/1] = c*128 + ((lk*2+e)^x)*16
  int dsoff[4][2];
#pragma unroll
  for (int j = 0; j < 4; ++j) {
    int c = j * 16 + lrow, x = c & 7;
    dsoff[j][0] = c * 128 + (((lk * 2)     ^ x) * 16);
    dsoff[j][1] = c * 128 + (((lk * 2 + 1) ^ x) * 16);
  }

  const int nbase = chunk * 1024;

  // one global_load_lds (16B/thread) for half h: 2 per thread per half.
  // LDS 16B-unit swizzle: phys u_p holds logical u_l = u_p ^ (col&7).
  auto issue1 = [&](unsigned char* dst, int h, int it) {
    int off16 = it * 256 + tid;          // [0,512) 16B units
    int col = off16 >> 3, up = off16 & 7;
    int ul = up ^ (col & 7);
    const unsigned char* src = Fq + (size_t)(nbase + h * 64 + col) * 128 + ul * 16;
    __builtin_amdgcn_global_load_lds((const AS1 void*)src,
                                     (AS3 void*)(dst + off16 * 16), 16, 0, 0);
  };

  // 4 super-phases of one PAIR; stage next pair (4 issues, 1 per phase)
  auto pair_body = [&](const unsigned char* sbA, const unsigned char* sbB,
                       bool doStage, int nslot, int hnext) {
#pragma unroll
    for (int j = 0; j < 4; ++j) {
      int8v b8A, b8B;
      ((int4v*)&b8A)[0] = *(const int4v*)(sbA + dsoff[j][0]);
      ((int4v*)&b8A)[1] = *(const int4v*)(sbA + dsoff[j][1]);
      ((int4v*)&b8B)[0] = *(const int4v*)(sbB + dsoff[j][0]);
      ((int4v*)&b8B)[1] = *(const int4v*)(sbB + dsoff[j][1]);
      if (doStage)
        issue1(&ring[nslot + (j >> 1)][0], hnext + (j >> 1), j & 1);
      f32x4 accA[4], accB[4];
#pragma unroll
      for (int mf = 0; mf < 4; ++mf)
        accA[mf] = __builtin_amdgcn_mfma_scale_f32_16x16x128_f8f6f4(
            af[mf], b8A, cinit, 0, 0, 0, SCLA, 0, SCLB);
#pragma unroll
      for (int mf = 0; mf < 4; ++mf)
        accB[mf] = __builtin_amdgcn_mfma_scale_f32_16x16x128_f8f6f4(
            af[mf], b8B, cinit, 0, 0, 0, SCLA, 0, SCLB);
      // acc holds (20*cos - 20)*log2e: one exp2 per logit, vector adds
#pragma unroll
      for (int mf = 0; mf < 4; ++mf) {
        f32x4 e;
        e[0] = __builtin_amdgcn_exp2f(accA[mf][0]);
        e[1] = __builtin_amdgcn_exp2f(accA[mf][1]);
        e[2] = __builtin_amdgcn_exp2f(accA[mf][2]);
        e[3] = __builtin_amdgcn_exp2f(accA[mf][3]);
        racc[mf] += e;
      }
#pragma unroll
      for (int mf = 0; mf < 4; ++mf) {
        f32x4 e;
        e[0] = __builtin_amdgcn_exp2f(accB[mf][0]);
        e[1] = __builtin_amdgcn_exp2f(accB[mf][1]);
        e[2] = __builtin_amdgcn_exp2f(accB[mf][2]);
        e[3] = __builtin_amdgcn_exp2f(accB[mf][3]);
        racc[mf] += e;
      }
    }
  };

  // prologue: pair 0 (halves 0,1) in flight (4 loads/thread)
  issue1(&ring[0][0], 0, 0);
  issue1(&ring[0][0], 0, 1);
  issue1(&ring[1][0], 1, 0);
  issue1(&ring[1][0], 1, 1);

#pragma unroll 1
  for (int i = 0; i < 8; ++i) {
    // pair i's 4 loads are the only outstanding ones -> vmcnt(0) retires
    // them; barrier also closes iter i-1's reads of the slots we stage into
    asm volatile("s_waitcnt vmcnt(0)" ::: "memory");
    __builtin_amdgcn_s_barrier();
    int s0 = (i & 1) * 2;
    int n0 = 2 - s0;
    pair_body(&ring[s0][0], &ring[s0 + 1][0], i < 7, n0, 2 * i + 2);
  }

  // reduce across 16 lanes per row, transpose via LDS, coalesced store
#pragma unroll
  for (int mf = 0; mf < 4; ++mf)
#pragma unroll
    for (int j = 0; j < 4; ++j) {
      float v = racc[mf][j];
      v += __shfl_xor(v, 1, 64);
      v += __shfl_xor(v, 2, 64);
      v += __shfl_xor(v, 4, 64);
      v += __shfl_xor(v, 8, 64);
      if (lrow == 0) xpose[wid][mf * 16 + lk * 4 + j] = v;
    }
  __syncthreads();
  part[(size_t)chunk * NROWS + row0 + lane] = xpose[wid][lane];
}

// ---- fused tail, ONE dispatch: 8 blocks x 1024 threads ----
// Each block owns 256 rows; 4 chunk-groups of 256 threads each sum ~25
// chunks (reads coalesced within a group); groups combine via LDS; group 0
// computes 20 + log(tot) - picked, wave-reduces, one atomicAdd per block.
__global__ void k_tail(const float* __restrict__ part, const float* __restrict__ picked,
                       float* __restrict__ out) {
  __shared__ float psum[4][256];
  __shared__ float red[4];
  int tid = threadIdx.x;
  int sub = tid >> 8;                // chunk-group [0,4)
  int r   = tid & 255;               // row within block
  int b   = blockIdx.x * 256 + r;
  int c0 = sub * 25;
  int c1 = (sub == 3) ? NCHUNK : c0 + 25;
  float s = 0.f;
  for (int c = c0; c < c1; ++c) s += part[(size_t)c * NROWS + b];
  psum[sub][r] = s;
  __syncthreads();
  if (sub == 0) {
    float tot = psum[0][r] + psum[1][r] + psum[2][r] + psum[3][r] - PADC;
    float lb = 20.0f + logf(tot) - picked[b];
#pragma unroll
    for (int m = 1; m < 64; m <<= 1) lb += __shfl_xor(lb, m, 64);
    if ((tid & 63) == 0) red[tid >> 6] = lb;
  }
  __syncthreads();
  if (tid == 0)
    atomicAdd(out, (red[0] + red[1] + red[2] + red[3]) * (1.0f / 2048.0f));
}

extern "C" void kernel_launch(void* const* d_in, const int* in_sizes, int n_in,
                              void* d_out, int out_size, void* d_ws, size_t ws_size,
                              hipStream_t stream) {
  const float* inputs  = (const float*)d_in[0];
  const int*   indexes = (const int*)d_in[1];
  const int*   labels  = (const int*)d_in[2];
  const float* feats   = (const float*)d_in[3];
  float* out = (float*)d_out;

  char* ws = (char*)d_ws;
  unsigned short* A8 = (unsigned short*)(ws + 0);        // 2048*128   = 262,144 B
  unsigned char*  Fq = (unsigned char*)(ws + 262144);    // 100352*128 = 12,845,056 B
  float* part   = (float*)(ws + 13107200);               // 98*2048*4  = 802,816 B
  float* picked = (float*)(ws + 13910016);               // 2048*4

  hipMemsetAsync(out, 0, sizeof(float), stream);
  hipLaunchKernelGGL(k_pc,   dim3(2080), dim3(256),  0, stream, inputs, indexes, labels, feats, A8, picked, Fq);
  hipLaunchKernelGGL(k_gemm, dim3(832),  dim3(256),  0, stream, A8, Fq, part);
  hipLaunchKernelGGL(k_tail, dim3(8),    dim3(1024), 0, stream, part, picked, out);
}

// Round 29
// 62.023 us; speedup vs baseline: 1.1685x; 1.1685x over previous
//
#include <hip/hip_runtime.h>

typedef float f32x4 __attribute__((ext_vector_type(4)));
typedef int   int4v __attribute__((ext_vector_type(4)));
typedef int   int8v __attribute__((ext_vector_type(8)));

#define AS1 __attribute__((address_space(1)))
#define AS3 __attribute__((address_space(3)))

#define NROWS 2048
#define NCOLS 100000
#define NPAD  100352              // 98 chunks * 1024
#define NCHUNK 98
#define K2C  28.853900817779268f  // 20 * log2(e)
#define PADC 7.2552607e-7f        // 352 * exp(-20): pad-column bias
#define SCLA 0x7F7F7F7Fu          // E8M0 scale 2^0  (A already x K2C)
#define SCLB 0x7C7C7C7Cu          // E8M0 scale 2^-3 (B pre-scaled x 8)

// ---- merged prep (blocks 0..511) + feature f32->fp8 conv (rest) ----
__global__ void k_pc(const float* __restrict__ X, const int* __restrict__ idx,
                     const int* __restrict__ lab, const float* __restrict__ F,
                     unsigned short* __restrict__ A8, float* __restrict__ picked,
                     unsigned char* __restrict__ Fq) {
  if (blockIdx.x < 512) {
    // normalize inputs, scale by K2C, convert to fp8 e4m3; also picked
    int wid = threadIdx.x >> 6, lane = threadIdx.x & 63;
    int row = blockIdx.x * 4 + wid;
    int t = lab[idx[row]];
    float2 v = ((const float2*)(X + (size_t)row * 128))[lane];
    float2 f = ((const float2*)(F + (size_t)t * 128))[lane];
    float ss = v.x * v.x + v.y * v.y;
    float dp = v.x * f.x + v.y * f.y;
#pragma unroll
    for (int m = 1; m < 64; m <<= 1) {
      ss += __shfl_xor(ss, m, 64);
      dp += __shfl_xor(dp, m, 64);
    }
    float invn = 1.0f / fmaxf(sqrtf(ss), 1e-12f);
    float s = invn * K2C;             // fold 20*log2(e) into A
    int w = __builtin_amdgcn_cvt_pk_fp8_f32(v.x * s, v.y * s, 0, false);
    A8[row * 64 + lane] = (unsigned short)(w & 0xFFFF);
    if (lane == 0) picked[row] = 20.0f * dp * invn;
  } else {
    // features f32 -> fp8 e4m3 (x8), zero-pad [100000,100352)
    const int NG16 = NPAD * 8;   // 802,816 groups of 16 output bytes
    const int NV16 = NCOLS * 8;  // 800,000 valid groups
    int stride = 1568 * 256;
    for (int g = (blockIdx.x - 512) * 256 + threadIdx.x; g < NG16; g += stride) {
      float4 a = make_float4(0.f, 0.f, 0.f, 0.f), b = a, c = a, d = a;
      if (g < NV16) {
        const float4* p = (const float4*)F + 4 * (size_t)g;
        a = p[0]; b = p[1]; c = p[2]; d = p[3];
      }
      int w0 = __builtin_amdgcn_cvt_pk_fp8_f32(a.x * 8.f, a.y * 8.f, 0, false);
      w0 = __builtin_amdgcn_cvt_pk_fp8_f32(a.z * 8.f, a.w * 8.f, w0, true);
      int w1 = __builtin_amdgcn_cvt_pk_fp8_f32(b.x * 8.f, b.y * 8.f, 0, false);
      w1 = __builtin_amdgcn_cvt_pk_fp8_f32(b.z * 8.f, b.w * 8.f, w1, true);
      int w2 = __builtin_amdgcn_cvt_pk_fp8_f32(c.x * 8.f, c.y * 8.f, 0, false);
      w2 = __builtin_amdgcn_cvt_pk_fp8_f32(c.z * 8.f, c.w * 8.f, w2, true);
      int w3 = __builtin_amdgcn_cvt_pk_fp8_f32(d.x * 8.f, d.y * 8.f, 0, false);
      w3 = __builtin_amdgcn_cvt_pk_fp8_f32(d.z * 8.f, d.w * 8.f, w3, true);
      ((int4v*)Fq)[g] = (int4v){w0, w1, w2, w3};
    }
  }
}

// ---- fused GEMM + sum of exp(logit - 20), MX-fp8 K=128, PAIRED HALVES ----
// grid = 832 = 8 xcd * 104 slots; all 8 m-tiles of a chunk share one XCD.
// Ring of 4 x 8KB slots (32 KB); halves processed in PAIRS: super-phase j
// interleaves phase j of half 2i and 2i+1 -> TWO independent dep chains
// (8 indep MFMAs + 32 exp2) fill each other's MFMA-latency shadow within
// the wave. One vmcnt(0)+barrier per pair (prefetch lead = full pair).
// Best measured config (r25, 62.7us total). Practical plateau: per-phase
// chain {ds_read -> MFMA -> exp2 tail} unbreakable without a second acc
// set (+32-64 VGPR, crosses the 128-VGPR occupancy boundary; r11/r20).
__global__ __launch_bounds__(256, 2) void k_gemm(
    const unsigned short* __restrict__ A8,
    const unsigned char* __restrict__ Fq,
    float* __restrict__ part) {
  __shared__ unsigned char ring[4][64 * 128];     // 32 KB ring (fp8)
  __shared__ float xpose[4][64];                  // part-store transpose
  const int tid = threadIdx.x;
  const int wid = tid >> 6, lane = tid & 63;
  const int lrow = lane & 15, lk = lane >> 4;

  const int slot = blockIdx.x >> 3;     // [0,104)
  const int xcd  = blockIdx.x & 7;
  const int mtile = slot & 7;
  const int chunk = (slot >> 3) * 8 + xcd;
  if (chunk >= NCHUNK) return;
  const int row0 = mtile * 256 + wid * 64;

  // A fragments: 32 fp8 (full K strip) per lane per mf-tile = 32 VGPR total
  const unsigned char* A8b = (const unsigned char*)A8;
  int8v af[4];
#pragma unroll
  for (int mf = 0; mf < 4; ++mf) {
    const unsigned char* ap = A8b + (size_t)(row0 + mf * 16 + lrow) * 128 + lk * 32;
    ((int4v*)&af[mf])[0] = *(const int4v*)ap;
    ((int4v*)&af[mf])[1] = *(const int4v*)(ap + 16);
  }

  // vector accumulators -> v_pk_add_f32
  f32x4 racc[4];
#pragma unroll
  for (int mf = 0; mf < 4; ++mf) racc[mf] = (f32x4){0.f, 0.f, 0.f, 0.f};

  // loop-invariant C operand: folds the -20 shift
  f32x4 cinit = (f32x4){-K2C, -K2C, -K2C, -K2C};

  // hoisted ds_read lane offsets: off[j][0/1] = c*128 + ((lk*2+e)^x)*16
  int dsoff[4][2];
#pragma unroll
  for (int j = 0; j < 4; ++j) {
    int c = j * 16 + lrow, x = c & 7;
    dsoff[j][0] = c * 128 + (((lk * 2)     ^ x) * 16);
    dsoff[j][1] = c * 128 + (((lk * 2 + 1) ^ x) * 16);
  }

  const int nbase = chunk * 1024;

  // one global_load_lds (16B/thread) for half h: 2 per thread per half.
  // LDS 16B-unit swizzle: phys u_p holds logical u_l = u_p ^ (col&7).
  auto issue1 = [&](unsigned char* dst, int h, int it) {
    int off16 = it * 256 + tid;          // [0,512) 16B units
    int col = off16 >> 3, up = off16 & 7;
    int ul = up ^ (col & 7);
    const unsigned char* src = Fq + (size_t)(nbase + h * 64 + col) * 128 + ul * 16;
    __builtin_amdgcn_global_load_lds((const AS1 void*)src,
                                     (AS3 void*)(dst + off16 * 16), 16, 0, 0);
  };

  // 4 super-phases of one PAIR; stage next pair (4 issues, 1 per phase)
  auto pair_body = [&](const unsigned char* sbA, const unsigned char* sbB,
                       bool doStage, int nslot, int hnext) {
#pragma unroll
    for (int j = 0; j < 4; ++j) {
      int8v b8A, b8B;
      ((int4v*)&b8A)[0] = *(const int4v*)(sbA + dsoff[j][0]);
      ((int4v*)&b8A)[1] = *(const int4v*)(sbA + dsoff[j][1]);
      ((int4v*)&b8B)[0] = *(const int4v*)(sbB + dsoff[j][0]);
      ((int4v*)&b8B)[1] = *(const int4v*)(sbB + dsoff[j][1]);
      if (doStage)
        issue1(&ring[nslot + (j >> 1)][0], hnext + (j >> 1), j & 1);
      f32x4 accA[4], accB[4];
#pragma unroll
      for (int mf = 0; mf < 4; ++mf)
        accA[mf] = __builtin_amdgcn_mfma_scale_f32_16x16x128_f8f6f4(
            af[mf], b8A, cinit, 0, 0, 0, SCLA, 0, SCLB);
#pragma unroll
      for (int mf = 0; mf < 4; ++mf)
        accB[mf] = __builtin_amdgcn_mfma_scale_f32_16x16x128_f8f6f4(
            af[mf], b8B, cinit, 0, 0, 0, SCLA, 0, SCLB);
      // acc holds (20*cos - 20)*log2e: one exp2 per logit, vector adds
#pragma unroll
      for (int mf = 0; mf < 4; ++mf) {
        f32x4 e;
        e[0] = __builtin_amdgcn_exp2f(accA[mf][0]);
        e[1] = __builtin_amdgcn_exp2f(accA[mf][1]);
        e[2] = __builtin_amdgcn_exp2f(accA[mf][2]);
        e[3] = __builtin_amdgcn_exp2f(accA[mf][3]);
        racc[mf] += e;
      }
#pragma unroll
      for (int mf = 0; mf < 4; ++mf) {
        f32x4 e;
        e[0] = __builtin_amdgcn_exp2f(accB[mf][0]);
        e[1] = __builtin_amdgcn_exp2f(accB[mf][1]);
        e[2] = __builtin_amdgcn_exp2f(accB[mf][2]);
        e[3] = __builtin_amdgcn_exp2f(accB[mf][3]);
        racc[mf] += e;
      }
    }
  };

  // prologue: pair 0 (halves 0,1) in flight (4 loads/thread)
  issue1(&ring[0][0], 0, 0);
  issue1(&ring[0][0], 0, 1);
  issue1(&ring[1][0], 1, 0);
  issue1(&ring[1][0], 1, 1);

#pragma unroll 1
  for (int i = 0; i < 8; ++i) {
    // pair i's 4 loads are the only outstanding ones -> vmcnt(0) retires
    // them; barrier also closes iter i-1's reads of the slots we stage into
    asm volatile("s_waitcnt vmcnt(0)" ::: "memory");
    __builtin_amdgcn_s_barrier();
    int s0 = (i & 1) * 2;
    int n0 = 2 - s0;
    pair_body(&ring[s0][0], &ring[s0 + 1][0], i < 7, n0, 2 * i + 2);
  }

  // reduce across 16 lanes per row, transpose via LDS, coalesced store
#pragma unroll
  for (int mf = 0; mf < 4; ++mf)
#pragma unroll
    for (int j = 0; j < 4; ++j) {
      float v = racc[mf][j];
      v += __shfl_xor(v, 1, 64);
      v += __shfl_xor(v, 2, 64);
      v += __shfl_xor(v, 4, 64);
      v += __shfl_xor(v, 8, 64);
      if (lrow == 0) xpose[wid][mf * 16 + lk * 4 + j] = v;
    }
  __syncthreads();
  part[(size_t)chunk * NROWS + row0 + lane] = xpose[wid][lane];
}

// ---- stage 1 reduction: 56 blocks, each sums 14 chunks for 256 rows ----
__global__ void k_loss1(const float* __restrict__ part, float* __restrict__ psum) {
  int rb = blockIdx.x & 7, cb = blockIdx.x >> 3;   // cb in [0,7)
  int b = rb * 256 + threadIdx.x;
  float s = 0.f;
#pragma unroll
  for (int k = 0; k < 14; ++k)
    s += part[(size_t)(cb * 14 + k) * NROWS + b];
  psum[(size_t)cb * NROWS + b] = s;
}

// ---- final: per-row logz - picked, mean ----
__global__ void k_final(const float* __restrict__ psum, const float* __restrict__ picked,
                        float* __restrict__ out) {
  int tid = threadIdx.x;
  float lb = 0.f;
#pragma unroll
  for (int rr = 0; rr < 2; ++rr) {
    int b = rr * 1024 + tid;
    float tot = 0.f;
#pragma unroll
    for (int cb = 0; cb < 7; ++cb) tot += psum[(size_t)cb * NROWS + b];
    tot -= PADC;                     // remove pad-column contribution
    lb += 20.0f + logf(tot) - picked[b];
  }
#pragma unroll
  for (int m = 1; m < 64; m <<= 1) lb += __shfl_xor(lb, m, 64);
  __shared__ float red[16];
  if ((tid & 63) == 0) red[tid >> 6] = lb;
  __syncthreads();
  if (tid == 0) {
    float s = 0.f;
#pragma unroll
    for (int i = 0; i < 16; ++i) s += red[i];
    out[0] = s * (1.0f / 2048.0f);
  }
}

extern "C" void kernel_launch(void* const* d_in, const int* in_sizes, int n_in,
                              void* d_out, int out_size, void* d_ws, size_t ws_size,
                              hipStream_t stream) {
  const float* inputs  = (const float*)d_in[0];
  const int*   indexes = (const int*)d_in[1];
  const int*   labels  = (const int*)d_in[2];
  const float* feats   = (const float*)d_in[3];
  float* out = (float*)d_out;

  char* ws = (char*)d_ws;
  unsigned short* A8 = (unsigned short*)(ws + 0);        // 2048*128   = 262,144 B
  unsigned char*  Fq = (unsigned char*)(ws + 262144);    // 100352*128 = 12,845,056 B
  float* part   = (float*)(ws + 13107200);               // 98*2048*4  = 802,816 B
  float* psum   = (float*)(ws + 13910016);               // 7*2048*4   = 57,344 B
  float* picked = (float*)(ws + 13967360);               // 2048*4

  hipLaunchKernelGGL(k_pc,    dim3(2080), dim3(256),  0, stream, inputs, indexes, labels, feats, A8, picked, Fq);
  hipLaunchKernelGGL(k_gemm,  dim3(832),  dim3(256),  0, stream, A8, Fq, part);
  hipLaunchKernelGGL(k_loss1, dim3(56),   dim3(256),  0, stream, part, psum);
  hipLaunchKernelGGL(k_final, dim3(1),    dim3(1024), 0, stream, psum, picked, out);
}